// Round 2
// 546.643 us; speedup vs baseline: 1.0142x; 1.0142x over previous
//
#include <hip/hip_runtime.h>

// BatchConv2DLayer: per-sample 3x3 conv, stride 1, pad 1, fp32 in/out.
// 3-kernel pipeline:
//   1) transpose_kernel: x NCHW fp32 -> xt NHWC bf16 (d_ws)
//   2) wconv_kernel:     weights fp32 [b][co][ci][3][3] -> bf16 [b][co][tap][ci]
//   3) conv_mfma_kernel: implicit-GEMM, mfma_f32_16x16x32_bf16, XOR-swizzled
//      LDS x-tile (conflict-free ds_read_b128), each wave does both co halves
//      per B-read (2 MFMA per ds_read), A-frags direct from L2-hot global.

#define BB 32
#define CI 32
#define CO 32
#define HH 256
#define WW 256

typedef unsigned int uint;
using short8  = __attribute__((ext_vector_type(8))) short;
using float4v = __attribute__((ext_vector_type(4))) float;

__device__ inline unsigned short f2bf(float f) {
    union { float f; uint u; } c; c.f = f;
    uint r = c.u + 0x7fffu + ((c.u >> 16) & 1u);   // round-to-nearest-even
    return (unsigned short)(r >> 16);
}

// ---------------------------------------------------------------------------
// Kernel 1: x [b][ci][h][w] fp32  ->  xt [b][h][w][ci] bf16 (into d_ws)
// Block = one (b,h): 32ci x 256w. LDS tile[ci][w] fp32, row stride 260.
// Memory-bound already (~400MB total traffic); unchanged from prior round.
// ---------------------------------------------------------------------------
__global__ __launch_bounds__(256)
void transpose_kernel(const float* __restrict__ x,
                      unsigned short* __restrict__ xt) {
    __shared__ float tile[CI * 260];
    const int h = blockIdx.x;
    const int b = blockIdx.y;
    const int t = threadIdx.x;

    const float* xp = x + (size_t)b * CI * HH * WW + (size_t)h * WW;
    #pragma unroll
    for (int i = 0; i < 8; ++i) {
        int idx = t + 256 * i;          // 0..2047
        int w4  = idx & 63;             // float4 index along w
        int ci  = idx >> 6;
        float4 v = *(const float4*)(xp + (size_t)ci * HH * WW + w4 * 4);
        *(float4*)(&tile[ci * 260 + w4 * 4]) = v;
    }
    __syncthreads();

    // Thread t emits pixel w=t: 32 ci as bf16 packed into 16 dwords.
    const int w = t;
    uint dw[16];
    #pragma unroll
    for (int j = 0; j < 16; ++j) {
        uint lo = f2bf(tile[(2 * j) * 260 + w]);
        uint hi = f2bf(tile[(2 * j + 1) * 260 + w]);
        dw[j] = lo | (hi << 16);
    }
    unsigned short* op = xt + (((size_t)(b * HH + h)) * WW + w) * CI;
    #pragma unroll
    for (int q = 0; q < 4; ++q) {
        uint4 v = make_uint4(dw[4*q+0], dw[4*q+1], dw[4*q+2], dw[4*q+3]);
        *(uint4*)(op + q * 8) = v;
    }
}

// ---------------------------------------------------------------------------
// Kernel 2: weight pre-convert. wgt fp32 [b][co][ci][3][3] ->
// wb bf16 [b][co][tap][ci]. 294912 elements total; one shot, ~2us.
// Removes 9216 f2bf + int-div decode per conv block (x8192 blocks).
// ---------------------------------------------------------------------------
__global__ __launch_bounds__(256)
void wconv_kernel(const float* __restrict__ wgt,
                  unsigned short* __restrict__ wb) {
    const int i = blockIdx.x * 256 + threadIdx.x;   // 0..294911
    const int bc  = i / 288;          // b*32+co
    const int rem = i - bc * 288;
    const int ci  = rem / 9;
    const int tap = rem - ci * 9;
    wb[(bc * 9 + tap) * CI + ci] = f2bf(wgt[i]);
}

// ---------------------------------------------------------------------------
// Kernel 3: implicit-GEMM conv. Block = (b, 8-row x 32-col output tile),
// 256 threads = 4 waves. LDS: x tile 10x34 pixels x 32ci bf16 (21.76KB),
// XOR-swizzled: byte ^= ((pix>>1)&3)<<4. Wave wv owns pixel-groups
// wv*4..wv*4+3 and BOTH co halves: per tap one swizzled ds_read_b128
// feeds 2 MFMAs. A-frags (18x short8) loaded from global (L2-hot, 18KB/b).
// mfma_f32_16x16x32_bf16 layouts (guide §3, m89/m91-verified):
//   A[m=lane&15][k=(lane>>4)*8+j]  (m=co, k=ci)
//   B[k=(lane>>4)*8+j][n=lane&15]  (n=pixel)
//   D: col(n)=lane&15, row(m)=(lane>>4)*4+reg
// ---------------------------------------------------------------------------
#define TH 8
#define TW 32
#define XR (TH + 2)
#define XC (TW + 2)

__device__ inline int swz_us(int pix, int q) {
    // ushort index of 16B quad q of pixel pix, bank-conflict-free swizzle
    return pix * CI + (((q ^ (pix >> 1)) & 3) << 3);
}

__global__ __launch_bounds__(256)
void conv_mfma_kernel(const unsigned short* __restrict__ xt,
                      const unsigned short* __restrict__ wb,
                      const float* __restrict__ bias,
                      float* __restrict__ out) {
    __shared__ __align__(16) unsigned short xs[XR * XC * CI];   // 21760 B

    const int tw = blockIdx.x;   // 0..7
    const int th = blockIdx.y;   // 0..31
    const int b  = blockIdx.z;
    const int t  = threadIdx.x;
    const int h0 = th * TH, w0 = tw * TW;

    const int wv  = t >> 6;
    const int l   = t & 63;
    const int lp  = l & 15;            // A:m(co offset) == B:n(pixel)
    const int lq  = l >> 4;            // quad -> k = lq*8+j

    // A-frags straight from global (issue early; L2-hot per b).
    const unsigned short* wbb = wb + (size_t)(b * CO) * 9 * CI;
    short8 A0[9], A1[9];
    #pragma unroll
    for (int tp = 0; tp < 9; ++tp) {
        A0[tp] = *(const short8*)(wbb + ((lp)      * 9 + tp) * CI + lq * 8);
        A1[tp] = *(const short8*)(wbb + ((16 + lp) * 9 + tp) * CI + lq * 8);
    }

    // Stage x tile (rows h0-1..h0+8, cols w0-1..w0+32), zero-pad OOB,
    // swizzled ds_write_b128 (conflict-free: 8 lanes = 2 pixels x 4 quads).
    for (int i = t; i < XR * XC * 4; i += 256) {
        int q   = i & 3;          // 16B quad within pixel's 64B
        int pix = i >> 2;
        int r   = pix / XC;
        int c   = pix - r * XC;
        int h   = h0 - 1 + r;
        int w   = w0 - 1 + c;
        uint4 v = make_uint4(0, 0, 0, 0);
        if (h >= 0 && h < HH && w >= 0 && w < WW) {
            v = *(const uint4*)(xt + (((size_t)(b * HH + h)) * WW + w) * CI + q * 8);
        }
        *(uint4*)(&xs[swz_us(pix, q)]) = v;
    }
    __syncthreads();

    float4v acc0[4], acc1[4];
    #pragma unroll
    for (int g = 0; g < 4; ++g) {
        acc0[g] = {0.f, 0.f, 0.f, 0.f};
        acc1[g] = {0.f, 0.f, 0.f, 0.f};
    }

    #pragma unroll
    for (int g = 0; g < 4; ++g) {
        const int gg = wv * 4 + g;
        const int r  = gg >> 1;          // local output row 0..7
        const int c0 = (gg & 1) * 16;    // local output col base
        #pragma unroll
        for (int kh = 0; kh < 3; ++kh) {
            #pragma unroll
            for (int kw = 0; kw < 3; ++kw) {
                const int p = (r + kh) * XC + (c0 + lp + kw);
                short8 Bf = *(const short8*)(&xs[swz_us(p, lq)]);
                acc0[g] = __builtin_amdgcn_mfma_f32_16x16x32_bf16(
                    A0[kh * 3 + kw], Bf, acc0[g], 0, 0, 0);
                acc1[g] = __builtin_amdgcn_mfma_f32_16x16x32_bf16(
                    A1[kh * 3 + kw], Bf, acc1[g], 0, 0, 0);
            }
        }
    }

    // Epilogue: D row(co within half) = lq*4 + v, col(pixel) = lp.
    float bv0[4], bv1[4];
    #pragma unroll
    for (int v = 0; v < 4; ++v) {
        bv0[v] = bias[b * CO + lq * 4 + v];
        bv1[v] = bias[b * CO + 16 + lq * 4 + v];
    }

    #pragma unroll
    for (int g = 0; g < 4; ++g) {
        const int gg = wv * 4 + g;
        const int r  = gg >> 1;
        const int c0 = (gg & 1) * 16;
        const int h  = h0 + r;
        const int wpix = w0 + c0 + lp;
        #pragma unroll
        for (int v = 0; v < 4; ++v) {
            const int co_l = lq * 4 + v;
            out[(((size_t)(b * CO + co_l)) * HH + h) * WW + wpix] =
                acc0[g][v] + bv0[v];
            out[(((size_t)(b * CO + 16 + co_l)) * HH + h) * WW + wpix] =
                acc1[g][v] + bv1[v];
        }
    }
}

// ---------------------------------------------------------------------------
// Fallback (direct fp32 conv) if ws is too small for the bf16 NHWC copy.
// ---------------------------------------------------------------------------
#define FHT 16
#define FXR (FHT + 2)
#define LROW 264

__global__ __launch_bounds__(256)
void conv3x3_fallback(const float* __restrict__ x,
                      const float* __restrict__ wgt,
                      const float* __restrict__ bias,
                      float* __restrict__ out) {
    __shared__ float xs[FXR * LROW];
    __shared__ float wsh[CI * 9];
    const int co = blockIdx.x;
    const int ht = blockIdx.y;
    const int b  = blockIdx.z;
    const int tid = threadIdx.x;
    const int h0 = ht * FHT;
    for (int i = tid; i < CI * 9; i += 256)
        wsh[i] = wgt[((size_t)(b * CO + co) * CI) * 9 + i];
    for (int i = tid; i < FXR * 8; i += 256) {
        int row = i >> 3; int c = i & 7;
        int col = (c < 4) ? c : (256 + c);
        xs[row * LROW + col] = 0.0f;
    }
    const int wg = tid & 63, rp = tid >> 6;
    const int w0 = wg * 4, r0 = rp * 4;
    float acc[4][4];
    #pragma unroll
    for (int d = 0; d < 4; ++d)
        #pragma unroll
        for (int j = 0; j < 4; ++j) acc[d][j] = 0.0f;
    const float* xb = x + (size_t)(b * CI) * HH * WW;
    for (int ci = 0; ci < CI; ++ci) {
        __syncthreads();
        const float* xsrc = xb + (size_t)ci * HH * WW;
        for (int i = tid; i < FXR * 64; i += 256) {
            int row = i >> 6; int cq = i & 63;
            int gh = h0 - 1 + row;
            float4 v = make_float4(0.f, 0.f, 0.f, 0.f);
            if (gh >= 0 && gh < HH)
                v = *(const float4*)(xsrc + (size_t)gh * WW + cq * 4);
            *(float4*)(&xs[row * LROW + 4 + cq * 4]) = v;
        }
        __syncthreads();
        float wk[9];
        #pragma unroll
        for (int k = 0; k < 9; ++k) wk[k] = wsh[ci * 9 + k];
        #pragma unroll
        for (int xr = 0; xr < 6; ++xr) {
            const float* rowp = &xs[(r0 + xr) * LROW + w0];
            float xv[12];
            #pragma unroll
            for (int q = 0; q < 3; ++q) {
                float4 v = *(const float4*)(rowp + 4 * q);
                xv[4*q+0] = v.x; xv[4*q+1] = v.y; xv[4*q+2] = v.z; xv[4*q+3] = v.w;
            }
            #pragma unroll
            for (int dr = 0; dr < 4; ++dr) {
                const int kh = xr - dr;
                if (kh < 0 || kh > 2) continue;
                #pragma unroll
                for (int kw = 0; kw < 3; ++kw) {
                    const float wvv = wk[kh * 3 + kw];
                    #pragma unroll
                    for (int j = 0; j < 4; ++j)
                        acc[dr][j] += xv[j + kw + 3] * wvv;
                }
            }
        }
    }
    const float bv = bias[b * CO + co];
    float* ob = out + ((size_t)(b * CO + co) * HH + (h0 + r0)) * WW + w0;
    #pragma unroll
    for (int dr = 0; dr < 4; ++dr) {
        float4 o;
        o.x = acc[dr][0] + bv; o.y = acc[dr][1] + bv;
        o.z = acc[dr][2] + bv; o.w = acc[dr][3] + bv;
        *(float4*)(ob + (size_t)dr * WW) = o;
    }
}

extern "C" void kernel_launch(void* const* d_in, const int* in_sizes, int n_in,
                              void* d_out, int out_size, void* d_ws, size_t ws_size,
                              hipStream_t stream) {
    const float* x    = (const float*)d_in[0];
    const float* wgt  = (const float*)d_in[1];
    const float* bias = (const float*)d_in[2];
    float* out        = (float*)d_out;

    const size_t xt_elems = (size_t)BB * HH * WW * CI;            // 64M shorts
    const size_t wb_elems = (size_t)BB * CO * 9 * CI;             // 294912 shorts
    const size_t need = (xt_elems + wb_elems) * sizeof(unsigned short);
    if (ws_size >= need) {
        unsigned short* xtp = (unsigned short*)d_ws;
        unsigned short* wbp = xtp + xt_elems;
        hipLaunchKernelGGL(transpose_kernel, dim3(HH, BB), dim3(256), 0, stream,
                           x, xtp);
        hipLaunchKernelGGL(wconv_kernel, dim3((BB * CO * CI * 9) / 256), dim3(256),
                           0, stream, wgt, wbp);
        hipLaunchKernelGGL(conv_mfma_kernel, dim3(WW / TW, HH / TH, BB), dim3(256),
                           0, stream, xtp, wbp, bias, out);
    } else {
        hipLaunchKernelGGL(conv3x3_fallback, dim3(CO, HH / FHT, BB), dim3(256),
                           0, stream, x, wgt, bias, out);
    }
}

// Round 3
// 503.479 us; speedup vs baseline: 1.1012x; 1.0857x over previous
//
#include <hip/hip_runtime.h>

// BatchConv2DLayer: per-sample 3x3 conv, stride 1, pad 1, fp32 in/out.
// 2-kernel pipeline (transpose pass FUSED into conv this round):
//   1) wconv_kernel: weights fp32 [b][co][ci][3][3] -> bf16 [b][co][tap][ci]
//   2) conv_fused_kernel: reads x (NCHW fp32) directly, converts to bf16
//      NHWC in the XOR-swizzled LDS tile in-register, then implicit-GEMM
//      with mfma_f32_16x16x32_bf16 (2 MFMA per ds_read_b128, both co halves
//      per wave). Eliminates the 134MB xt write + 178MB re-read.

#define BB 32
#define CI 32
#define CO 32
#define HH 256
#define WW 256

typedef unsigned int uint;
using short8  = __attribute__((ext_vector_type(8))) short;
using float4v = __attribute__((ext_vector_type(4))) float;

__device__ inline unsigned short f2bf(float f) {
    union { float f; uint u; } c; c.f = f;
    uint r = c.u + 0x7fffu + ((c.u >> 16) & 1u);   // round-to-nearest-even
    return (unsigned short)(r >> 16);
}

// ---------------------------------------------------------------------------
// Kernel 1: weight pre-convert. wgt fp32 [b][co][ci][3][3] ->
// wb bf16 [b][co][tap][ci]. 294912 elements, one shot, ~2us.
// ---------------------------------------------------------------------------
__global__ __launch_bounds__(256)
void wconv_kernel(const float* __restrict__ wgt,
                  unsigned short* __restrict__ wb) {
    const int i = blockIdx.x * 256 + threadIdx.x;   // 0..294911
    const int bc  = i / 288;          // b*32+co
    const int rem = i - bc * 288;
    const int ci  = rem / 9;
    const int tap = rem - ci * 9;
    wb[(bc * 9 + tap) * CI + ci] = f2bf(wgt[i]);
}

// ---------------------------------------------------------------------------
// Kernel 2: fused convert+conv. Block = (b, 8-row x 32-col output tile),
// 256 threads = 4 waves. LDS x tile 10x34 pixels x 32ci bf16 (21.76KB),
// XOR-swizzled (quad q of pixel p stored at slot q^((p>>1)&3)).
// Staging: 1600 work items (ci2 0..15, row 0..9, f 0..9); each loads two
// aligned float4 of x rows (ci, ci+1) at cols w0-4+4f.., converts, writes
// packed bf16 ci-pairs via ds_write_b32 into the swizzled tile (zero-pad OOB).
// Compute: per wave 4 pixel-groups x both co halves: one swizzled
// ds_read_b128 B-frag feeds 2 MFMAs. A-frags from global (L2-hot, 18KB/b).
// mfma_f32_16x16x32_bf16 layouts (guide §3, m89/m91-verified):
//   A[m=lane&15][k=(lane>>4)*8+j]  (m=co, k=ci)
//   B[k=(lane>>4)*8+j][n=lane&15]  (n=pixel)
//   D: col(n)=lane&15, row(m)=(lane>>4)*4+reg
// ---------------------------------------------------------------------------
#define TH 8
#define TW 32
#define XR (TH + 2)
#define XC (TW + 2)

__device__ inline int swz_us(int pix, int q) {
    // ushort index of 16B quad q of pixel pix, bank-conflict-free swizzle
    return pix * CI + (((q ^ (pix >> 1)) & 3) << 3);
}

__global__ __launch_bounds__(256)
void conv_fused_kernel(const float* __restrict__ x,
                       const unsigned short* __restrict__ wb,
                       const float* __restrict__ bias,
                       float* __restrict__ out) {
    __shared__ __align__(16) unsigned short xs[XR * XC * CI];   // 21760 B

    const int tw = blockIdx.x;   // 0..7
    const int th = blockIdx.y;   // 0..31
    const int b  = blockIdx.z;
    const int t  = threadIdx.x;
    const int h0 = th * TH, w0 = tw * TW;

    const int wv  = t >> 6;
    const int l   = t & 63;
    const int lp  = l & 15;            // A:m(co offset) == B:n(pixel)
    const int lq  = l >> 4;            // quad -> k = lq*8+j

    // A-frags straight from global (issue early; L2-hot per b).
    const unsigned short* wbb = wb + (size_t)(b * CO) * 9 * CI;
    short8 A0[9], A1[9];
    #pragma unroll
    for (int tp = 0; tp < 9; ++tp) {
        A0[tp] = *(const short8*)(wbb + ((lp)      * 9 + tp) * CI + lq * 8);
        A1[tp] = *(const short8*)(wbb + ((16 + lp) * 9 + tp) * CI + lq * 8);
    }

    // ---- Fused staging: x fp32 NCHW -> swizzled bf16 NHWC tile in LDS ----
    // Work item i = (ci2, row, f): rows h0-1+row, aligned cols w0-4+4f..+3,
    // channels 2*ci2 and 2*ci2+1. In-tile cols are w0-1..w0+32 (local 0..33).
    const float* xb = x + (size_t)b * CI * HH * WW;
    for (int i = t; i < 1600; i += 256) {
        const int f   = i % 10;
        const int rr  = (i / 10) % 10;
        const int ci2 = i / 100;          // 0..15
        const int ci  = ci2 * 2;
        const int h   = h0 - 1 + rr;
        const int c4  = w0 - 4 + 4 * f;   // aligned float4 col base
        float4 va = make_float4(0.f, 0.f, 0.f, 0.f);
        float4 vc = make_float4(0.f, 0.f, 0.f, 0.f);
        if (h >= 0 && h < HH && c4 >= 0 && c4 < WW) {
            const float* p0 = xb + (size_t)ci * HH * WW + (size_t)h * WW + c4;
            va = *(const float4*)p0;
            vc = *(const float4*)(p0 + (size_t)HH * WW);
        }
        const float ae[4] = {va.x, va.y, va.z, va.w};
        const float ce[4] = {vc.x, vc.y, vc.z, vc.w};
        #pragma unroll
        for (int e = 0; e < 4; ++e) {
            const int cl = 4 * f + e - 3;     // local col, valid 0..33
            if (cl >= 0 && cl < XC) {
                const int p = rr * XC + cl;
                const uint val = (uint)f2bf(ae[e]) | ((uint)f2bf(ce[e]) << 16);
                const int idx = p * CI + (((ci >> 3) ^ ((p >> 1) & 3)) << 3)
                              + (ci & 7);     // even -> 4B aligned
                *(uint*)(&xs[idx]) = val;
            }
        }
    }
    __syncthreads();

    float4v acc0[4], acc1[4];
    #pragma unroll
    for (int g = 0; g < 4; ++g) {
        acc0[g] = {0.f, 0.f, 0.f, 0.f};
        acc1[g] = {0.f, 0.f, 0.f, 0.f};
    }

    #pragma unroll
    for (int g = 0; g < 4; ++g) {
        const int gg = wv * 4 + g;
        const int r  = gg >> 1;          // local output row 0..7
        const int c0 = (gg & 1) * 16;    // local output col base
        #pragma unroll
        for (int kh = 0; kh < 3; ++kh) {
            #pragma unroll
            for (int kw = 0; kw < 3; ++kw) {
                const int p = (r + kh) * XC + (c0 + lp + kw);
                short8 Bf = *(const short8*)(&xs[swz_us(p, lq)]);
                acc0[g] = __builtin_amdgcn_mfma_f32_16x16x32_bf16(
                    A0[kh * 3 + kw], Bf, acc0[g], 0, 0, 0);
                acc1[g] = __builtin_amdgcn_mfma_f32_16x16x32_bf16(
                    A1[kh * 3 + kw], Bf, acc1[g], 0, 0, 0);
            }
        }
    }

    // Epilogue: D row(co within half) = lq*4 + v, col(pixel) = lp.
    float bv0[4], bv1[4];
    #pragma unroll
    for (int v = 0; v < 4; ++v) {
        bv0[v] = bias[b * CO + lq * 4 + v];
        bv1[v] = bias[b * CO + 16 + lq * 4 + v];
    }

    #pragma unroll
    for (int g = 0; g < 4; ++g) {
        const int gg = wv * 4 + g;
        const int r  = gg >> 1;
        const int c0 = (gg & 1) * 16;
        const int h  = h0 + r;
        const int wpix = w0 + c0 + lp;
        #pragma unroll
        for (int v = 0; v < 4; ++v) {
            const int co_l = lq * 4 + v;
            out[(((size_t)(b * CO + co_l)) * HH + h) * WW + wpix] =
                acc0[g][v] + bv0[v];
            out[(((size_t)(b * CO + 16 + co_l)) * HH + h) * WW + wpix] =
                acc1[g][v] + bv1[v];
        }
    }
}

// ---------------------------------------------------------------------------
// Fallback (direct fp32 conv) if ws is too small for the bf16 weights.
// ---------------------------------------------------------------------------
#define FHT 16
#define FXR (FHT + 2)
#define LROW 264

__global__ __launch_bounds__(256)
void conv3x3_fallback(const float* __restrict__ x,
                      const float* __restrict__ wgt,
                      const float* __restrict__ bias,
                      float* __restrict__ out) {
    __shared__ float xs[FXR * LROW];
    __shared__ float wsh[CI * 9];
    const int co = blockIdx.x;
    const int ht = blockIdx.y;
    const int b  = blockIdx.z;
    const int tid = threadIdx.x;
    const int h0 = ht * FHT;
    for (int i = tid; i < CI * 9; i += 256)
        wsh[i] = wgt[((size_t)(b * CO + co) * CI) * 9 + i];
    for (int i = tid; i < FXR * 8; i += 256) {
        int row = i >> 3; int c = i & 7;
        int col = (c < 4) ? c : (256 + c);
        xs[row * LROW + col] = 0.0f;
    }
    const int wg = tid & 63, rp = tid >> 6;
    const int w0 = wg * 4, r0 = rp * 4;
    float acc[4][4];
    #pragma unroll
    for (int d = 0; d < 4; ++d)
        #pragma unroll
        for (int j = 0; j < 4; ++j) acc[d][j] = 0.0f;
    const float* xb = x + (size_t)(b * CI) * HH * WW;
    for (int ci = 0; ci < CI; ++ci) {
        __syncthreads();
        const float* xsrc = xb + (size_t)ci * HH * WW;
        for (int i = tid; i < FXR * 64; i += 256) {
            int row = i >> 6; int cq = i & 63;
            int gh = h0 - 1 + row;
            float4 v = make_float4(0.f, 0.f, 0.f, 0.f);
            if (gh >= 0 && gh < HH)
                v = *(const float4*)(xsrc + (size_t)gh * WW + cq * 4);
            *(float4*)(&xs[row * LROW + 4 + cq * 4]) = v;
        }
        __syncthreads();
        float wk[9];
        #pragma unroll
        for (int k = 0; k < 9; ++k) wk[k] = wsh[ci * 9 + k];
        #pragma unroll
        for (int xr = 0; xr < 6; ++xr) {
            const float* rowp = &xs[(r0 + xr) * LROW + w0];
            float xv[12];
            #pragma unroll
            for (int q = 0; q < 3; ++q) {
                float4 v = *(const float4*)(rowp + 4 * q);
                xv[4*q+0] = v.x; xv[4*q+1] = v.y; xv[4*q+2] = v.z; xv[4*q+3] = v.w;
            }
            #pragma unroll
            for (int dr = 0; dr < 4; ++dr) {
                const int kh = xr - dr;
                if (kh < 0 || kh > 2) continue;
                #pragma unroll
                for (int kw = 0; kw < 3; ++kw) {
                    const float wvv = wk[kh * 3 + kw];
                    #pragma unroll
                    for (int j = 0; j < 4; ++j)
                        acc[dr][j] += xv[j + kw + 3] * wvv;
                }
            }
        }
    }
    const float bv = bias[b * CO + co];
    float* ob = out + ((size_t)(b * CO + co) * HH + (h0 + r0)) * WW + w0;
    #pragma unroll
    for (int dr = 0; dr < 4; ++dr) {
        float4 o;
        o.x = acc[dr][0] + bv; o.y = acc[dr][1] + bv;
        o.z = acc[dr][2] + bv; o.w = acc[dr][3] + bv;
        *(float4*)(ob + (size_t)dr * WW) = o;
    }
}

extern "C" void kernel_launch(void* const* d_in, const int* in_sizes, int n_in,
                              void* d_out, int out_size, void* d_ws, size_t ws_size,
                              hipStream_t stream) {
    const float* x    = (const float*)d_in[0];
    const float* wgt  = (const float*)d_in[1];
    const float* bias = (const float*)d_in[2];
    float* out        = (float*)d_out;

    const size_t wb_bytes = (size_t)BB * CO * 9 * CI * sizeof(unsigned short);
    if (ws_size >= wb_bytes) {
        unsigned short* wbp = (unsigned short*)d_ws;
        hipLaunchKernelGGL(wconv_kernel, dim3((BB * CO * CI * 9) / 256), dim3(256),
                           0, stream, wgt, wbp);
        hipLaunchKernelGGL(conv_fused_kernel, dim3(WW / TW, HH / TH, BB), dim3(256),
                           0, stream, x, wbp, bias, out);
    } else {
        hipLaunchKernelGGL(conv3x3_fallback, dim3(CO, HH / FHT, BB), dim3(256),
                           0, stream, x, wgt, bias, out);
    }
}

// Round 4
// 493.798 us; speedup vs baseline: 1.1228x; 1.0196x over previous
//
#include <hip/hip_runtime.h>

// BatchConv2DLayer: per-sample 3x3 conv, stride 1, pad 1, fp32 in/out.
// 2-kernel pipeline:
//   1) wconv_kernel: weights fp32 [b][co][ci][3][3] -> bf16 [b][co][tap][ci]
//   2) conv_fused_kernel: 16x32 output tile, 512 thr. Reads x (NCHW fp32)
//      directly, v_cvt_pk_bf16_f32 -> XOR-swizzled LDS NHWC tile
//      (ds_write_b128), implicit-GEMM mfma_f32_16x16x32_bf16 with
//      A=pixels / B=weights so D rows = consecutive w -> dwordx4 stores.

#define BB 32
#define CI 32
#define CO 32
#define HH 256
#define WW 256

typedef unsigned int uint;
using short8  = __attribute__((ext_vector_type(8))) short;
using float4v = __attribute__((ext_vector_type(4))) float;

__device__ inline unsigned short f2bf(float f) {
    union { float f; uint u; } c; c.f = f;
    uint r = c.u + 0x7fffu + ((c.u >> 16) & 1u);   // round-to-nearest-even
    return (unsigned short)(r >> 16);
}

// v_cvt_pk_bf16_f32: lo -> D[15:0], hi -> D[31:16], RNE (no builtin on gfx950)
__device__ inline uint pk2bf(float lo, float hi) {
    uint r;
    asm("v_cvt_pk_bf16_f32 %0, %1, %2" : "=v"(r) : "v"(lo), "v"(hi));
    return r;
}

// ---------------------------------------------------------------------------
// Kernel 1: weight pre-convert. wgt fp32 [b][co][ci][3][3] ->
// wb bf16 [b][co][tap][ci]. 294912 elements, one shot, ~2us.
// ---------------------------------------------------------------------------
__global__ __launch_bounds__(256)
void wconv_kernel(const float* __restrict__ wgt,
                  unsigned short* __restrict__ wb) {
    const int i = blockIdx.x * 256 + threadIdx.x;   // 0..294911
    const int bc  = i / 288;          // b*32+co
    const int rem = i - bc * 288;
    const int ci  = rem / 9;
    const int tap = rem - ci * 9;
    wb[(bc * 9 + tap) * CI + ci] = f2bf(wgt[i]);
}

// ---------------------------------------------------------------------------
// Kernel 2: fused convert+conv. Block = (b, 16-row x 32-col tile), 512 thr
// (8 waves). LDS x tile 18 rows x 40 cols x 32ci bf16 = 46080 B, aligned to
// the float4 grid (tile col c <-> global w = w0 + c - 4; no col predicate).
// Swizzle: ci-quad q of pixel p stored at quad-slot q ^ ((p>>1)&3).
// Staging item (rr, f, ciq): 8x float4 global loads (ci=ciq*8+j, 4 cols),
// cvt_pk to bf16, 4x ds_write_b128 (one per pixel).
// Compute: wave wv owns pixel-groups wv*4..+3, both co halves: per tap one
// swizzled ds_read_b128 pixel-frag feeds 2 MFMAs (A=pixels, B=weights).
// mfma_f32_16x16x32_bf16 layouts (guide §3, m89/m91-verified):
//   A[m=lane&15][k=(lane>>4)*8+j]  (m=pixel, k=ci)
//   B[k=(lane>>4)*8+j][n=lane&15]  (n=co)
//   D: col(n=co)=lane&15, row(m=pixel)=(lane>>4)*4+reg  -> 4 consecutive w
// ---------------------------------------------------------------------------
#define TH 16
#define TW 32
#define XR (TH + 2)   // 18 rows
#define XC 40         // aligned cols: w0-4 .. w0+35

__device__ inline int swz_us(int pix, int q) {
    // ushort index of 16B quad-slot q^((pix>>1)&3) of pixel pix
    return pix * CI + (((q ^ (pix >> 1)) & 3) << 3);
}

__global__ __launch_bounds__(512)
void conv_fused_kernel(const float* __restrict__ x,
                       const unsigned short* __restrict__ wb,
                       const float* __restrict__ bias,
                       float* __restrict__ out) {
    __shared__ __align__(16) unsigned short xs[XR * XC * CI];   // 46080 B

    const int tw = blockIdx.x;   // 0..7
    const int th = blockIdx.y;   // 0..15
    const int b  = blockIdx.z;
    const int t  = threadIdx.x;
    const int h0 = th * TH, w0 = tw * TW;

    const int wv  = t >> 6;            // 0..7
    const int l   = t & 63;
    const int lp  = l & 15;            // A:m(pixel) == B:n(co)
    const int lq  = l >> 4;            // quad -> k = lq*8+j

    // Weight B-frags from global (L2-hot, 18KB per image).
    const unsigned short* wbb = wb + (size_t)(b * CO) * 9 * CI;
    short8 W0[9], W1[9];
    #pragma unroll
    for (int tp = 0; tp < 9; ++tp) {
        W0[tp] = *(const short8*)(wbb + ((lp)      * 9 + tp) * CI + lq * 8);
        W1[tp] = *(const short8*)(wbb + ((16 + lp) * 9 + tp) * CI + lq * 8);
    }

    // ---- Fused staging: x fp32 NCHW -> swizzled bf16 NHWC tile in LDS ----
    // 720 items = 18 rows x 10 f4-cols x 4 ci-quads.
    const float* xb = x + (size_t)b * CI * HH * WW;
    for (int i = t; i < XR * 10 * 4; i += 512) {
        const int qd  = i / 10;          // 0..71
        const int f   = i - qd * 10;     // 0..9
        const int ciq = qd & 3;          // 0..3
        const int rr  = qd >> 2;         // 0..17
        const int h   = h0 - 1 + rr;
        const int c4  = w0 - 4 + 4 * f;
        float4v v[8];
        if (h >= 0 && h < HH && c4 >= 0 && c4 <= WW - 4) {
            const float* p0 = xb + (size_t)(ciq * 8) * HH * WW
                                 + (size_t)h * WW + c4;
            #pragma unroll
            for (int j = 0; j < 8; ++j)
                v[j] = *(const float4v*)(p0 + (size_t)j * HH * WW);
        } else {
            #pragma unroll
            for (int j = 0; j < 8; ++j) v[j] = {0.f, 0.f, 0.f, 0.f};
        }
        #pragma unroll
        for (int e = 0; e < 4; ++e) {
            const int p = rr * XC + 4 * f + e;
            uint4 pk;
            pk.x = pk2bf(v[0][e], v[1][e]);
            pk.y = pk2bf(v[2][e], v[3][e]);
            pk.z = pk2bf(v[4][e], v[5][e]);
            pk.w = pk2bf(v[6][e], v[7][e]);
            *(uint4*)(&xs[swz_us(p, ciq)]) = pk;
        }
    }
    __syncthreads();

    float4v acc0[4], acc1[4];
    #pragma unroll
    for (int g = 0; g < 4; ++g) {
        acc0[g] = {0.f, 0.f, 0.f, 0.f};
        acc1[g] = {0.f, 0.f, 0.f, 0.f};
    }

    #pragma unroll
    for (int g = 0; g < 4; ++g) {
        const int gg = wv * 4 + g;       // 0..31
        const int r  = gg >> 1;          // local output row 0..15
        const int c0 = (gg & 1) * 16;    // local output col base
        #pragma unroll
        for (int kh = 0; kh < 3; ++kh) {
            #pragma unroll
            for (int kw = 0; kw < 3; ++kw) {
                // input: global row h0+r+kh-1 = tile row r+kh;
                //        global col w0+c0+lp+kw-1 = tile col c0+lp+kw+3
                const int p = (r + kh) * XC + (c0 + lp + kw + 3);
                short8 Pf = *(const short8*)(&xs[swz_us(p, lq)]);
                acc0[g] = __builtin_amdgcn_mfma_f32_16x16x32_bf16(
                    Pf, W0[kh * 3 + kw], acc0[g], 0, 0, 0);
                acc1[g] = __builtin_amdgcn_mfma_f32_16x16x32_bf16(
                    Pf, W1[kh * 3 + kw], acc1[g], 0, 0, 0);
            }
        }
    }

    // Epilogue: lane holds co=lp (and 16+lp), pixels = c0 + lq*4 + v.
    const float bv0 = bias[b * CO + lp];
    const float bv1 = bias[b * CO + 16 + lp];

    #pragma unroll
    for (int g = 0; g < 4; ++g) {
        const int gg = wv * 4 + g;
        const int r  = gg >> 1;
        const int c0 = (gg & 1) * 16;
        const int h  = h0 + r;
        const int wb4 = w0 + c0 + lq * 4;
        float4v o0 = acc0[g] + bv0;
        float4v o1 = acc1[g] + bv1;
        *(float4v*)(&out[(((size_t)(b * CO + lp)) * HH + h) * WW + wb4]) = o0;
        *(float4v*)(&out[(((size_t)(b * CO + 16 + lp)) * HH + h) * WW + wb4]) = o1;
    }
}

// ---------------------------------------------------------------------------
// Fallback (direct fp32 conv) if ws is too small for the bf16 weights.
// ---------------------------------------------------------------------------
#define FHT 16
#define FXR (FHT + 2)
#define LROW 264

__global__ __launch_bounds__(256)
void conv3x3_fallback(const float* __restrict__ x,
                      const float* __restrict__ wgt,
                      const float* __restrict__ bias,
                      float* __restrict__ out) {
    __shared__ float xs[FXR * LROW];
    __shared__ float wsh[CI * 9];
    const int co = blockIdx.x;
    const int ht = blockIdx.y;
    const int b  = blockIdx.z;
    const int tid = threadIdx.x;
    const int h0 = ht * FHT;
    for (int i = tid; i < CI * 9; i += 256)
        wsh[i] = wgt[((size_t)(b * CO + co) * CI) * 9 + i];
    for (int i = tid; i < FXR * 8; i += 256) {
        int row = i >> 3; int c = i & 7;
        int col = (c < 4) ? c : (256 + c);
        xs[row * LROW + col] = 0.0f;
    }
    const int wg = tid & 63, rp = tid >> 6;
    const int w0 = wg * 4, r0 = rp * 4;
    float acc[4][4];
    #pragma unroll
    for (int d = 0; d < 4; ++d)
        #pragma unroll
        for (int j = 0; j < 4; ++j) acc[d][j] = 0.0f;
    const float* xb = x + (size_t)(b * CI) * HH * WW;
    for (int ci = 0; ci < CI; ++ci) {
        __syncthreads();
        const float* xsrc = xb + (size_t)ci * HH * WW;
        for (int i = tid; i < FXR * 64; i += 256) {
            int row = i >> 6; int cq = i & 63;
            int gh = h0 - 1 + row;
            float4 v = make_float4(0.f, 0.f, 0.f, 0.f);
            if (gh >= 0 && gh < HH)
                v = *(const float4*)(xsrc + (size_t)gh * WW + cq * 4);
            *(float4*)(&xs[row * LROW + 4 + cq * 4]) = v;
        }
        __syncthreads();
        float wk[9];
        #pragma unroll
        for (int k = 0; k < 9; ++k) wk[k] = wsh[ci * 9 + k];
        #pragma unroll
        for (int xr = 0; xr < 6; ++xr) {
            const float* rowp = &xs[(r0 + xr) * LROW + w0];
            float xv[12];
            #pragma unroll
            for (int q = 0; q < 3; ++q) {
                float4 v = *(const float4*)(rowp + 4 * q);
                xv[4*q+0] = v.x; xv[4*q+1] = v.y; xv[4*q+2] = v.z; xv[4*q+3] = v.w;
            }
            #pragma unroll
            for (int dr = 0; dr < 4; ++dr) {
                const int kh = xr - dr;
                if (kh < 0 || kh > 2) continue;
                #pragma unroll
                for (int kw = 0; kw < 3; ++kw) {
                    const float wvv = wk[kh * 3 + kw];
                    #pragma unroll
                    for (int j = 0; j < 4; ++j)
                        acc[dr][j] += xv[j + kw + 3] * wvv;
                }
            }
        }
    }
    const float bv = bias[b * CO + co];
    float* ob = out + ((size_t)(b * CO + co) * HH + (h0 + r0)) * WW + w0;
    #pragma unroll
    for (int dr = 0; dr < 4; ++dr) {
        float4 o;
        o.x = acc[dr][0] + bv; o.y = acc[dr][1] + bv;
        o.z = acc[dr][2] + bv; o.w = acc[dr][3] + bv;
        *(float4*)(ob + (size_t)dr * WW) = o;
    }
}

extern "C" void kernel_launch(void* const* d_in, const int* in_sizes, int n_in,
                              void* d_out, int out_size, void* d_ws, size_t ws_size,
                              hipStream_t stream) {
    const float* x    = (const float*)d_in[0];
    const float* wgt  = (const float*)d_in[1];
    const float* bias = (const float*)d_in[2];
    float* out        = (float*)d_out;

    const size_t wb_bytes = (size_t)BB * CO * 9 * CI * sizeof(unsigned short);
    if (ws_size >= wb_bytes) {
        unsigned short* wbp = (unsigned short*)d_ws;
        hipLaunchKernelGGL(wconv_kernel, dim3((BB * CO * CI * 9) / 256), dim3(256),
                           0, stream, wgt, wbp);
        hipLaunchKernelGGL(conv_fused_kernel, dim3(WW / TW, HH / TH, BB), dim3(512),
                           0, stream, x, wbp, bias, out);
    } else {
        hipLaunchKernelGGL(conv3x3_fallback, dim3(CO, HH / FHT, BB), dim3(256),
                           0, stream, x, wgt, bias, out);
    }
}